// Round 3
// baseline (584.185 us; speedup 1.0000x reference)
//
#include <hip/hip_runtime.h>

#define D 128
#define C 40
#define SCAN_B 256

// ---- init: cnt=0, cursor=0 ----
__global__ void zero2_kernel(int* __restrict__ cnt, int* __restrict__ cursor, int n) {
    int i = blockIdx.x * blockDim.x + threadIdx.x;
    if (i < n) { cnt[i] = 0; cursor[i] = 0; }
}

// ---- histogram of dst ----
__global__ void count_kernel(const int* __restrict__ dst, int* __restrict__ cnt, int E) {
    int e = blockIdx.x * blockDim.x + threadIdx.x;
    if (e < E) atomicAdd(&cnt[dst[e]], 1);
}

// ---- dis[i] = rsqrt(1 + cnt[i]) ----
__global__ void dis_kernel(const int* __restrict__ cnt, float* __restrict__ dis, int n) {
    int i = blockIdx.x * blockDim.x + threadIdx.x;
    if (i < n) dis[i] = rsqrtf(1.0f + (float)cnt[i]);
}

// ---- 3-kernel exclusive scan over cnt -> rowptr ----
__global__ void scan_block_kernel(const int* __restrict__ cnt, int* __restrict__ rowptr,
                                  int* __restrict__ bsum, int n) {
    __shared__ int s[SCAN_B];
    int i = blockIdx.x * SCAN_B + threadIdx.x;
    int v = (i < n) ? cnt[i] : 0;
    s[threadIdx.x] = v;
    __syncthreads();
    for (int off = 1; off < SCAN_B; off <<= 1) {
        int t = (threadIdx.x >= off) ? s[threadIdx.x - off] : 0;
        __syncthreads();
        s[threadIdx.x] += t;
        __syncthreads();
    }
    if (i < n) rowptr[i] = s[threadIdx.x] - v;  // exclusive within block
    if (threadIdx.x == SCAN_B - 1) bsum[blockIdx.x] = s[SCAN_B - 1];
}

__global__ void scan_bsum_kernel(int* __restrict__ bsum, int nb) {
    __shared__ int s[512];
    int v = (threadIdx.x < nb) ? bsum[threadIdx.x] : 0;
    s[threadIdx.x] = v;
    __syncthreads();
    for (int off = 1; off < 512; off <<= 1) {
        int t = (threadIdx.x >= off) ? s[threadIdx.x - off] : 0;
        __syncthreads();
        s[threadIdx.x] += t;
        __syncthreads();
    }
    if (threadIdx.x < nb) bsum[threadIdx.x] = s[threadIdx.x] - v;  // exclusive
}

__global__ void add_off_kernel(int* __restrict__ rowptr, const int* __restrict__ bsum,
                               int n, int E) {
    int i = blockIdx.x * blockDim.x + threadIdx.x;
    if (i < n) rowptr[i] += bsum[i >> 8];
    if (i == 0) rowptr[n] = E;
}

// ---- fill CSR: srcs only (norms computed on the fly in gather) ----
__global__ void fill_kernel(const int* __restrict__ src, const int* __restrict__ dst,
                            const int* __restrict__ rowptr, int* __restrict__ cursor,
                            int* __restrict__ srcs, int E) {
    int e = blockIdx.x * blockDim.x + threadIdx.x;
    if (e >= E) return;
    int s = src[e];
    int d = dst[e];
    int pos = rowptr[d] + atomicAdd(&cursor[d], 1);
    srcs[pos] = s;
}

// ---- one propagation hop: gather by destination, no atomics ----
// 32 lanes per node, one float4 per lane (D=128). Block = 256 -> 8 nodes.
// out[d,:] = dis[d] * ( dis[d]*x[d,:] + sum_e dis[src_e]*x[src_e,:] )
// 4x unrolled edge loop for memory-level parallelism.
__global__ void gather_hop_kernel(const float* __restrict__ xin, float* __restrict__ xout,
                                  const int* __restrict__ rowptr, const int* __restrict__ srcs,
                                  const float* __restrict__ dis, int n) {
    int node = blockIdx.x * 8 + (threadIdx.x >> 5);
    int t = threadIdx.x & 31;
    if (node >= n) return;
    const float4* xi = (const float4*)xin;
    float dd = dis[node];
    float4 xself = xi[(size_t)node * 32 + t];
    float4 acc;
    acc.x = dd * xself.x; acc.y = dd * xself.y; acc.z = dd * xself.z; acc.w = dd * xself.w;
    int beg = rowptr[node];
    int end = rowptr[node + 1];
    int e = beg;
    for (; e + 4 <= end; e += 4) {
        int s0 = srcs[e + 0];
        int s1 = srcs[e + 1];
        int s2 = srcs[e + 2];
        int s3 = srcs[e + 3];
        float w0 = dis[s0];
        float w1 = dis[s1];
        float w2 = dis[s2];
        float w3 = dis[s3];
        float4 v0 = xi[(size_t)s0 * 32 + t];
        float4 v1 = xi[(size_t)s1 * 32 + t];
        float4 v2 = xi[(size_t)s2 * 32 + t];
        float4 v3 = xi[(size_t)s3 * 32 + t];
        acc.x += w0 * v0.x; acc.y += w0 * v0.y; acc.z += w0 * v0.z; acc.w += w0 * v0.w;
        acc.x += w1 * v1.x; acc.y += w1 * v1.y; acc.z += w1 * v1.z; acc.w += w1 * v1.w;
        acc.x += w2 * v2.x; acc.y += w2 * v2.y; acc.z += w2 * v2.z; acc.w += w2 * v2.w;
        acc.x += w3 * v3.x; acc.y += w3 * v3.y; acc.z += w3 * v3.z; acc.w += w3 * v3.w;
    }
    for (; e < end; ++e) {
        int sv = srcs[e];
        float w = dis[sv];
        float4 v = xi[(size_t)sv * 32 + t];
        acc.x += w * v.x; acc.y += w * v.y; acc.z += w * v.z; acc.w += w * v.w;
    }
    acc.x *= dd; acc.y *= dd; acc.z *= dd; acc.w *= dd;
    ((float4*)xout)[(size_t)node * 32 + t] = acc;
}

// ---- head: tiled GEMM (32 nodes/block) + log_softmax ----
// Block = 256 threads. Each block: stage x-tile [32][132] + W [128][40] in LDS.
// Thread t: node = t>>3, owns 5 cols starting at (t&7)*5. Softmax reduced via
// __shfl_xor over the 8 lanes sharing a node.
#define HN 32   // nodes per block
__global__ void head_kernel(const float* __restrict__ x, const float* __restrict__ W,
                            const float* __restrict__ b, float* __restrict__ out, int n) {
    __shared__ float sX[HN * 132];   // padded stride 132 kills bank conflicts
    __shared__ float sW[D * C];
    __shared__ float sb[C];
    int tid = threadIdx.x;
    int base = blockIdx.x * HN;

    // stage W, b
    for (int i = tid; i < D * C; i += 256) sW[i] = W[i];
    if (tid < C) sb[tid] = b[tid];
    // stage x tile: HN*32 float4 loads, coalesced
    {
        const float4* xi = (const float4*)(x + (size_t)base * D);
        for (int i = tid; i < HN * 32; i += 256) {
            int r = i >> 5, c4 = i & 31;
            float4 v = xi[i];
            float* dstp = &sX[r * 132 + c4 * 4];
            dstp[0] = v.x; dstp[1] = v.y; dstp[2] = v.z; dstp[3] = v.w;
        }
    }
    __syncthreads();

    int nd = tid >> 3;            // 0..31 node within tile
    int cg = (tid & 7) * 5;       // first of 5 owned cols
    float acc[5];
#pragma unroll
    for (int j = 0; j < 5; ++j) acc[j] = sb[cg + j];
    const float* xr = &sX[nd * 132];
    for (int d = 0; d < D; ++d) {
        float xv = xr[d];
        const float* wr = &sW[d * C + cg];
#pragma unroll
        for (int j = 0; j < 5; ++j) acc[j] += xv * wr[j];
    }
    // log-softmax across the 8 lanes (40 cols)
    float m = acc[0];
#pragma unroll
    for (int j = 1; j < 5; ++j) m = fmaxf(m, acc[j]);
#pragma unroll
    for (int off = 1; off < 8; off <<= 1) m = fmaxf(m, __shfl_xor(m, off, 8));
    float ssum = 0.0f;
#pragma unroll
    for (int j = 0; j < 5; ++j) ssum += __expf(acc[j] - m);
#pragma unroll
    for (int off = 1; off < 8; off <<= 1) ssum += __shfl_xor(ssum, off, 8);
    float ls = logf(ssum) + m;
    int node = base + nd;
    if (node < n) {
        float* o = out + (size_t)node * C + cg;
#pragma unroll
        for (int j = 0; j < 5; ++j) o[j] = acc[j] - ls;
    }
}

extern "C" void kernel_launch(void* const* d_in, const int* in_sizes, int n_in,
                              void* d_out, int out_size, void* d_ws, size_t ws_size,
                              hipStream_t stream) {
    const float* x  = (const float*)d_in[0];
    const int*   ei = (const int*)d_in[1];   // [2, E] flat: row0 = src, row1 = dst
    const float* W  = (const float*)d_in[2]; // [D, C] row-major
    const float* b  = (const float*)d_in[3];
    float* out = (float*)d_out;

    const int N = in_sizes[0] / D;
    const int E = in_sizes[1] / 2;
    const int* src = ei;
    const int* dst = ei + E;

    // Workspace carve-up (256B-aligned chunks):
    // dis[N] | cnt[N] | cursor[N] | rowptr[N+1] | bsum[512] | srcs[E] |
    // buf0[N*D] | buf1[N*D]
    size_t npad = ((size_t)N + 256) & ~(size_t)255;
    char* p = (char*)d_ws;
    float* dis    = (float*)p;            p += npad * 4;
    int*   cnt    = (int*)p;              p += npad * 4;
    int*   cursor = (int*)p;              p += npad * 4;
    int*   rowptr = (int*)p;              p += npad * 4;
    int*   bsum   = (int*)p;              p += 512 * 4;
    size_t epad = ((size_t)E + 255) & ~(size_t)255;
    int*   srcs   = (int*)p;              p += epad * 4;
    float* buf0   = (float*)p;            p += (size_t)N * D * 4;
    float* buf1   = (float*)p;

    const int TB = 256;
    int nb_n = (N + TB - 1) / TB;
    int nb_e = (E + TB - 1) / TB;
    int nb_scan = (N + SCAN_B - 1) / SCAN_B;  // 391 <= 512

    // ---- CSR build ----
    zero2_kernel<<<nb_n, TB, 0, stream>>>(cnt, cursor, N);
    count_kernel<<<nb_e, TB, 0, stream>>>(dst, cnt, E);
    dis_kernel<<<nb_n, TB, 0, stream>>>(cnt, dis, N);
    scan_block_kernel<<<nb_scan, SCAN_B, 0, stream>>>(cnt, rowptr, bsum, N);
    scan_bsum_kernel<<<1, 512, 0, stream>>>(bsum, nb_scan);
    add_off_kernel<<<nb_n, TB, 0, stream>>>(rowptr, bsum, N, E);
    fill_kernel<<<nb_e, TB, 0, stream>>>(src, dst, rowptr, cursor, srcs, E);

    // ---- K=3 hops, ping-pong ----
    int nb_g = (N + 7) / 8;
    gather_hop_kernel<<<nb_g, TB, 0, stream>>>(x,    buf0, rowptr, srcs, dis, N);
    gather_hop_kernel<<<nb_g, TB, 0, stream>>>(buf0, buf1, rowptr, srcs, dis, N);
    gather_hop_kernel<<<nb_g, TB, 0, stream>>>(buf1, buf0, rowptr, srcs, dis, N);

    // ---- head ----
    int nb_h = (N + HN - 1) / HN;
    head_kernel<<<nb_h, 256, 0, stream>>>(buf0, W, b, out, N);
}

// Round 4
// 318.117 us; speedup vs baseline: 1.8364x; 1.8364x over previous
//
#include <hip/hip_runtime.h>

#define D 128
#define C 40
#define SCAN_B 256

// ---- init: cnt=0 ----
__global__ void zero_kernel(int* __restrict__ cnt, int n) {
    int i = blockIdx.x * blockDim.x + threadIdx.x;
    if (i < n) cnt[i] = 0;
}

// ---- histogram of dst + per-edge rank (position within its dst bucket) ----
__global__ void count_rank_kernel(const int* __restrict__ dst, int* __restrict__ cnt,
                                  int* __restrict__ rank, int E) {
    int e = blockIdx.x * blockDim.x + threadIdx.x;
    if (e < E) rank[e] = atomicAdd(&cnt[dst[e]], 1);
}

// ---- dis[i] = rsqrt(1 + cnt[i]) ----
__global__ void dis_kernel(const int* __restrict__ cnt, float* __restrict__ dis, int n) {
    int i = blockIdx.x * blockDim.x + threadIdx.x;
    if (i < n) dis[i] = rsqrtf(1.0f + (float)cnt[i]);
}

// ---- 3-kernel exclusive scan over cnt -> rowptr ----
__global__ void scan_block_kernel(const int* __restrict__ cnt, int* __restrict__ rowptr,
                                  int* __restrict__ bsum, int n) {
    __shared__ int s[SCAN_B];
    int i = blockIdx.x * SCAN_B + threadIdx.x;
    int v = (i < n) ? cnt[i] : 0;
    s[threadIdx.x] = v;
    __syncthreads();
    for (int off = 1; off < SCAN_B; off <<= 1) {
        int t = (threadIdx.x >= off) ? s[threadIdx.x - off] : 0;
        __syncthreads();
        s[threadIdx.x] += t;
        __syncthreads();
    }
    if (i < n) rowptr[i] = s[threadIdx.x] - v;  // exclusive within block
    if (threadIdx.x == SCAN_B - 1) bsum[blockIdx.x] = s[SCAN_B - 1];
}

__global__ void scan_bsum_kernel(int* __restrict__ bsum, int nb) {
    __shared__ int s[512];
    int v = (threadIdx.x < nb) ? bsum[threadIdx.x] : 0;
    s[threadIdx.x] = v;
    __syncthreads();
    for (int off = 1; off < 512; off <<= 1) {
        int t = (threadIdx.x >= off) ? s[threadIdx.x - off] : 0;
        __syncthreads();
        s[threadIdx.x] += t;
        __syncthreads();
    }
    if (threadIdx.x < nb) bsum[threadIdx.x] = s[threadIdx.x] - v;  // exclusive
}

__global__ void add_off_kernel(int* __restrict__ rowptr, const int* __restrict__ bsum,
                               int n, int E) {
    int i = blockIdx.x * blockDim.x + threadIdx.x;
    if (i < n) rowptr[i] += bsum[i >> 8];
    if (i == 0) rowptr[n] = E;
}

// ---- fill CSR: one scattered 4B store per edge (rank precomputed) ----
__global__ void fill_kernel(const int* __restrict__ src, const int* __restrict__ dst,
                            const int* __restrict__ rowptr, const int* __restrict__ rank,
                            int* __restrict__ srcs, int E) {
    int e = blockIdx.x * blockDim.x + threadIdx.x;
    if (e >= E) return;
    srcs[rowptr[dst[e]] + rank[e]] = src[e];
}

// ---- projection: Y = X @ W (no bias), Y row stride = 40 floats ----
// Block 256 = 32 nodes; x-tile + W staged in LDS; 8 lanes x 5 cols per node.
#define HN 32
__global__ void proj_kernel(const float* __restrict__ x, const float* __restrict__ W,
                            float* __restrict__ y, int n) {
    __shared__ float sX[HN * 132];   // padded stride kills bank conflicts
    __shared__ float sW[D * C];
    int tid = threadIdx.x;
    int base = blockIdx.x * HN;
    for (int i = tid; i < D * C; i += 256) sW[i] = W[i];
    {
        const float4* xi = (const float4*)(x + (size_t)base * D);
        for (int i = tid; i < HN * 32; i += 256) {
            int r = i >> 5, c4 = i & 31;
            float4 v = xi[i];
            float* dstp = &sX[r * 132 + c4 * 4];
            dstp[0] = v.x; dstp[1] = v.y; dstp[2] = v.z; dstp[3] = v.w;
        }
    }
    __syncthreads();
    int nd = tid >> 3;
    int cg = (tid & 7) * 5;
    float acc[5];
#pragma unroll
    for (int j = 0; j < 5; ++j) acc[j] = 0.0f;
    const float* xr = &sX[nd * 132];
    for (int d = 0; d < D; ++d) {
        float xv = xr[d];
        const float* wr = &sW[d * C + cg];
#pragma unroll
        for (int j = 0; j < 5; ++j) acc[j] += xv * wr[j];
    }
    int node = base + nd;
    if (node < n) {
        float* o = y + (size_t)node * C + cg;
#pragma unroll
        for (int j = 0; j < 5; ++j) o[j] = acc[j];
    }
}

// ---- one propagation hop on Y (C=40): 10 lanes per node, one float4 each ----
// yout[d,:] = dis[d] * ( dis[d]*y[d,:] + sum_e dis[src_e]*y[src_e,:] )
__global__ void gather40_kernel(const float* __restrict__ yin, float* __restrict__ yout,
                                const int* __restrict__ rowptr, const int* __restrict__ srcs,
                                const float* __restrict__ dis, int n) {
    int gtid = blockIdx.x * blockDim.x + threadIdx.x;
    int node = gtid / 10;
    int ch = gtid - node * 10;
    if (node >= n) return;
    const float4* yi = (const float4*)yin;
    float dd = dis[node];
    float4 self = yi[(size_t)node * 10 + ch];
    float4 acc;
    acc.x = dd * self.x; acc.y = dd * self.y; acc.z = dd * self.z; acc.w = dd * self.w;
    int beg = rowptr[node];
    int end = rowptr[node + 1];
    int e = beg;
    for (; e + 4 <= end; e += 4) {
        int s0 = srcs[e + 0], s1 = srcs[e + 1], s2 = srcs[e + 2], s3 = srcs[e + 3];
        float w0 = dis[s0], w1 = dis[s1], w2 = dis[s2], w3 = dis[s3];
        float4 v0 = yi[(size_t)s0 * 10 + ch];
        float4 v1 = yi[(size_t)s1 * 10 + ch];
        float4 v2 = yi[(size_t)s2 * 10 + ch];
        float4 v3 = yi[(size_t)s3 * 10 + ch];
        acc.x += w0 * v0.x; acc.y += w0 * v0.y; acc.z += w0 * v0.z; acc.w += w0 * v0.w;
        acc.x += w1 * v1.x; acc.y += w1 * v1.y; acc.z += w1 * v1.z; acc.w += w1 * v1.w;
        acc.x += w2 * v2.x; acc.y += w2 * v2.y; acc.z += w2 * v2.z; acc.w += w2 * v2.w;
        acc.x += w3 * v3.x; acc.y += w3 * v3.y; acc.z += w3 * v3.z; acc.w += w3 * v3.w;
    }
    for (; e < end; ++e) {
        int sv = srcs[e];
        float w = dis[sv];
        float4 v = yi[(size_t)sv * 10 + ch];
        acc.x += w * v.x; acc.y += w * v.y; acc.z += w * v.z; acc.w += w * v.w;
    }
    acc.x *= dd; acc.y *= dd; acc.z *= dd; acc.w *= dd;
    ((float4*)yout)[(size_t)node * 10 + ch] = acc;
}

// ---- final: out = log_softmax(y + b), 8 lanes x 5 cols per node ----
__global__ void lsm_kernel(const float* __restrict__ y, const float* __restrict__ b,
                           float* __restrict__ out, int n) {
    __shared__ float sb[C];
    int tid = threadIdx.x;
    if (tid < C) sb[tid] = b[tid];
    __syncthreads();
    int node = blockIdx.x * 32 + (tid >> 3);
    if (node >= n) return;
    int cg = (tid & 7) * 5;
    const float* yr = y + (size_t)node * C + cg;
    float acc[5];
#pragma unroll
    for (int j = 0; j < 5; ++j) acc[j] = yr[j] + sb[cg + j];
    float m = acc[0];
#pragma unroll
    for (int j = 1; j < 5; ++j) m = fmaxf(m, acc[j]);
#pragma unroll
    for (int off = 1; off < 8; off <<= 1) m = fmaxf(m, __shfl_xor(m, off, 8));
    float ssum = 0.0f;
#pragma unroll
    for (int j = 0; j < 5; ++j) ssum += __expf(acc[j] - m);
#pragma unroll
    for (int off = 1; off < 8; off <<= 1) ssum += __shfl_xor(ssum, off, 8);
    float ls = logf(ssum) + m;
    float* o = out + (size_t)node * C + cg;
#pragma unroll
    for (int j = 0; j < 5; ++j) o[j] = acc[j] - ls;
}

extern "C" void kernel_launch(void* const* d_in, const int* in_sizes, int n_in,
                              void* d_out, int out_size, void* d_ws, size_t ws_size,
                              hipStream_t stream) {
    const float* x  = (const float*)d_in[0];
    const int*   ei = (const int*)d_in[1];   // [2, E] flat: row0 = src, row1 = dst
    const float* W  = (const float*)d_in[2]; // [D, C] row-major
    const float* b  = (const float*)d_in[3];
    float* out = (float*)d_out;

    const int N = in_sizes[0] / D;
    const int E = in_sizes[1] / 2;
    const int* src = ei;
    const int* dst = ei + E;

    // Workspace: dis[N] | cnt[N] | rowptr[N+1] | bsum[512] | rank[E] | srcs[E] |
    //            ybuf0[N*C] | ybuf1[N*C]     (~46 MB)
    size_t npad = ((size_t)N + 256) & ~(size_t)255;
    size_t epad = ((size_t)E + 255) & ~(size_t)255;
    char* p = (char*)d_ws;
    float* dis    = (float*)p;  p += npad * 4;
    int*   cnt    = (int*)p;    p += npad * 4;
    int*   rowptr = (int*)p;    p += npad * 4;
    int*   bsum   = (int*)p;    p += 512 * 4;
    int*   rank   = (int*)p;    p += epad * 4;
    int*   srcs   = (int*)p;    p += epad * 4;
    float* ybuf0  = (float*)p;  p += (size_t)N * C * 4;
    float* ybuf1  = (float*)p;

    const int TB = 256;
    int nb_n = (N + TB - 1) / TB;
    int nb_e = (E + TB - 1) / TB;
    int nb_scan = (N + SCAN_B - 1) / SCAN_B;  // 391 <= 512

    // ---- CSR build ----
    zero_kernel<<<nb_n, TB, 0, stream>>>(cnt, N);
    count_rank_kernel<<<nb_e, TB, 0, stream>>>(dst, cnt, rank, E);
    dis_kernel<<<nb_n, TB, 0, stream>>>(cnt, dis, N);
    scan_block_kernel<<<nb_scan, SCAN_B, 0, stream>>>(cnt, rowptr, bsum, N);
    scan_bsum_kernel<<<1, 512, 0, stream>>>(bsum, nb_scan);
    add_off_kernel<<<nb_n, TB, 0, stream>>>(rowptr, bsum, N, E);
    fill_kernel<<<nb_e, TB, 0, stream>>>(src, dst, rowptr, rank, srcs, E);

    // ---- projection first (reassociation): Y = X W ----
    int nb_p = (N + HN - 1) / HN;
    proj_kernel<<<nb_p, 256, 0, stream>>>(x, W, ybuf0, N);

    // ---- K=3 hops on Y, ping-pong ----
    int nb_g = ((N * 10) + TB - 1) / TB;
    gather40_kernel<<<nb_g, TB, 0, stream>>>(ybuf0, ybuf1, rowptr, srcs, dis, N);
    gather40_kernel<<<nb_g, TB, 0, stream>>>(ybuf1, ybuf0, rowptr, srcs, dis, N);
    gather40_kernel<<<nb_g, TB, 0, stream>>>(ybuf0, ybuf1, rowptr, srcs, dis, N);

    // ---- bias + log_softmax ----
    int nb_l = (N + 31) / 32;
    lsm_kernel<<<nb_l, 256, 0, stream>>>(ybuf1, b, out, N);
}

// Round 5
// 283.953 us; speedup vs baseline: 2.0573x; 1.1203x over previous
//
#include <hip/hip_runtime.h>

#define D 128
#define C 40
#define SCAN_B 256
#define CSTRIDE 16   // cnt padded: 1 counter per 64B line to kill same-line atomic serialization

// ---- zero the padded histogram ----
__global__ void zero_kernel(int4* __restrict__ cnt16v, int n4) {
    int i = blockIdx.x * blockDim.x + threadIdx.x;
    if (i < n4) cnt16v[i] = make_int4(0, 0, 0, 0);
}

// ---- merged: count+rank (even-ish blocks) || projection Y = X W (odd-ish blocks) ----
// Roles are per-block uniform. Proj: 32 nodes/block, x-tile + W in LDS, 8 lanes x 5 cols.
#define HN 32
__global__ void count_proj_kernel(const int* __restrict__ dst, int* __restrict__ cnt16,
                                  int* __restrict__ rank, int E,
                                  const float* __restrict__ x, const float* __restrict__ W,
                                  float* __restrict__ y, int n, int nb_p) {
    __shared__ float sX[HN * 132];
    __shared__ float sW[D * C];
    int bid = blockIdx.x;
    int tid = threadIdx.x;
    int role, sub;  // role 0 = count, 1 = proj
    if (bid < 2 * nb_p) { role = bid & 1; sub = bid >> 1; }
    else { role = 0; sub = bid - nb_p; }

    if (role == 0) {
        int e = sub * 256 + tid;
        if (e < E) rank[e] = atomicAdd(&cnt16[(size_t)dst[e] * CSTRIDE], 1);
        return;
    }

    // ---- projection role ----
    int base = sub * HN;
    for (int i = tid; i < D * C; i += 256) sW[i] = W[i];
    {
        const float4* xi = (const float4*)(x + (size_t)base * D);
        for (int i = tid; i < HN * 32; i += 256) {
            int r = i >> 5, c4 = i & 31;
            float4 v = xi[i];
            float* dstp = &sX[r * 132 + c4 * 4];
            dstp[0] = v.x; dstp[1] = v.y; dstp[2] = v.z; dstp[3] = v.w;
        }
    }
    __syncthreads();
    int nd = tid >> 3;
    int cg = (tid & 7) * 5;
    float acc[5];
#pragma unroll
    for (int j = 0; j < 5; ++j) acc[j] = 0.0f;
    const float* xr = &sX[nd * 132];
    for (int d = 0; d < D; ++d) {
        float xv = xr[d];
        const float* wr = &sW[d * C + cg];
#pragma unroll
        for (int j = 0; j < 5; ++j) acc[j] += xv * wr[j];
    }
    int node = base + nd;
    if (node < n) {
        float* o = y + (size_t)node * C + cg;
#pragma unroll
        for (int j = 0; j < 5; ++j) o[j] = acc[j];
    }
}

// ---- exclusive scan over padded cnt -> rowptr; also emits dis = rsqrt(1+cnt) ----
__global__ void scan_block_kernel(const int* __restrict__ cnt16, int* __restrict__ rowptr,
                                  int* __restrict__ bsum, float* __restrict__ dis, int n) {
    __shared__ int s[SCAN_B];
    int i = blockIdx.x * SCAN_B + threadIdx.x;
    int v = (i < n) ? cnt16[(size_t)i * CSTRIDE] : 0;
    if (i < n) dis[i] = rsqrtf(1.0f + (float)v);
    s[threadIdx.x] = v;
    __syncthreads();
    for (int off = 1; off < SCAN_B; off <<= 1) {
        int t = (threadIdx.x >= off) ? s[threadIdx.x - off] : 0;
        __syncthreads();
        s[threadIdx.x] += t;
        __syncthreads();
    }
    if (i < n) rowptr[i] = s[threadIdx.x] - v;  // exclusive within block
    if (threadIdx.x == SCAN_B - 1) bsum[blockIdx.x] = s[SCAN_B - 1];
}

__global__ void scan_bsum_kernel(int* __restrict__ bsum, int nb) {
    __shared__ int s[512];
    int v = (threadIdx.x < nb) ? bsum[threadIdx.x] : 0;
    s[threadIdx.x] = v;
    __syncthreads();
    for (int off = 1; off < 512; off <<= 1) {
        int t = (threadIdx.x >= off) ? s[threadIdx.x - off] : 0;
        __syncthreads();
        s[threadIdx.x] += t;
        __syncthreads();
    }
    if (threadIdx.x < nb) bsum[threadIdx.x] = s[threadIdx.x] - v;  // exclusive
}

__global__ void add_off_kernel(int* __restrict__ rowptr, const int* __restrict__ bsum,
                               int n, int E) {
    int i = blockIdx.x * blockDim.x + threadIdx.x;
    if (i < n) rowptr[i] += bsum[i >> 8];
    if (i == 0) rowptr[n] = E;
}

// ---- fill CSR: one scattered 4B store per edge (rank precomputed) ----
__global__ void fill_kernel(const int* __restrict__ src, const int* __restrict__ dst,
                            const int* __restrict__ rowptr, const int* __restrict__ rank,
                            int* __restrict__ srcs, int E) {
    int e = blockIdx.x * blockDim.x + threadIdx.x;
    if (e >= E) return;
    srcs[rowptr[dst[e]] + rank[e]] = src[e];
}

// ---- one propagation hop on Y (C=40): 10 lanes per node, one float4 each ----
__global__ void gather40_kernel(const float* __restrict__ yin, float* __restrict__ yout,
                                const int* __restrict__ rowptr, const int* __restrict__ srcs,
                                const float* __restrict__ dis, int n) {
    int gtid = blockIdx.x * blockDim.x + threadIdx.x;
    int node = gtid / 10;
    int ch = gtid - node * 10;
    if (node >= n) return;
    const float4* yi = (const float4*)yin;
    float dd = dis[node];
    float4 self = yi[(size_t)node * 10 + ch];
    float4 acc;
    acc.x = dd * self.x; acc.y = dd * self.y; acc.z = dd * self.z; acc.w = dd * self.w;
    int beg = rowptr[node];
    int end = rowptr[node + 1];
    int e = beg;
    for (; e + 4 <= end; e += 4) {
        int s0 = srcs[e + 0], s1 = srcs[e + 1], s2 = srcs[e + 2], s3 = srcs[e + 3];
        float w0 = dis[s0], w1 = dis[s1], w2 = dis[s2], w3 = dis[s3];
        float4 v0 = yi[(size_t)s0 * 10 + ch];
        float4 v1 = yi[(size_t)s1 * 10 + ch];
        float4 v2 = yi[(size_t)s2 * 10 + ch];
        float4 v3 = yi[(size_t)s3 * 10 + ch];
        acc.x += w0 * v0.x; acc.y += w0 * v0.y; acc.z += w0 * v0.z; acc.w += w0 * v0.w;
        acc.x += w1 * v1.x; acc.y += w1 * v1.y; acc.z += w1 * v1.z; acc.w += w1 * v1.w;
        acc.x += w2 * v2.x; acc.y += w2 * v2.y; acc.z += w2 * v2.z; acc.w += w2 * v2.w;
        acc.x += w3 * v3.x; acc.y += w3 * v3.y; acc.z += w3 * v3.z; acc.w += w3 * v3.w;
    }
    for (; e < end; ++e) {
        int sv = srcs[e];
        float w = dis[sv];
        float4 v = yi[(size_t)sv * 10 + ch];
        acc.x += w * v.x; acc.y += w * v.y; acc.z += w * v.z; acc.w += w * v.w;
    }
    acc.x *= dd; acc.y *= dd; acc.z *= dd; acc.w *= dd;
    ((float4*)yout)[(size_t)node * 10 + ch] = acc;
}

// ---- final hop fused with bias + log_softmax. Block = 320 = 32 nodes x 10 lanes. ----
// Phase 1: gather acc (float4) -> LDS at float4 index tid (conflict-free).
// Phase 2: threads 0..255 re-read as 32 nodes x 8 lanes x 5 cols, shfl-8 softmax.
__global__ void __launch_bounds__(320)
gather40_lsm_kernel(const float* __restrict__ yin, const float* __restrict__ b,
                    float* __restrict__ out, const int* __restrict__ rowptr,
                    const int* __restrict__ srcs, const float* __restrict__ dis, int n) {
    __shared__ float sY[32 * C];
    __shared__ float sb[C];
    int tid = threadIdx.x;
    if (tid < C) sb[tid] = b[tid];
    int ndb = tid / 10;
    int ch = tid - ndb * 10;
    int node = blockIdx.x * 32 + ndb;
    if (node < n) {
        const float4* yi = (const float4*)yin;
        float dd = dis[node];
        float4 self = yi[(size_t)node * 10 + ch];
        float4 acc;
        acc.x = dd * self.x; acc.y = dd * self.y; acc.z = dd * self.z; acc.w = dd * self.w;
        int beg = rowptr[node];
        int end = rowptr[node + 1];
        int e = beg;
        for (; e + 4 <= end; e += 4) {
            int s0 = srcs[e + 0], s1 = srcs[e + 1], s2 = srcs[e + 2], s3 = srcs[e + 3];
            float w0 = dis[s0], w1 = dis[s1], w2 = dis[s2], w3 = dis[s3];
            float4 v0 = yi[(size_t)s0 * 10 + ch];
            float4 v1 = yi[(size_t)s1 * 10 + ch];
            float4 v2 = yi[(size_t)s2 * 10 + ch];
            float4 v3 = yi[(size_t)s3 * 10 + ch];
            acc.x += w0 * v0.x; acc.y += w0 * v0.y; acc.z += w0 * v0.z; acc.w += w0 * v0.w;
            acc.x += w1 * v1.x; acc.y += w1 * v1.y; acc.z += w1 * v1.z; acc.w += w1 * v1.w;
            acc.x += w2 * v2.x; acc.y += w2 * v2.y; acc.z += w2 * v2.z; acc.w += w2 * v2.w;
            acc.x += w3 * v3.x; acc.y += w3 * v3.y; acc.z += w3 * v3.z; acc.w += w3 * v3.w;
        }
        for (; e < end; ++e) {
            int sv = srcs[e];
            float w = dis[sv];
            float4 v = yi[(size_t)sv * 10 + ch];
            acc.x += w * v.x; acc.y += w * v.y; acc.z += w * v.z; acc.w += w * v.w;
        }
        acc.x *= dd; acc.y *= dd; acc.z *= dd; acc.w *= dd;
        ((float4*)sY)[tid] = acc;   // sY[ndb*40 + ch*4 .. +3] == float4 index tid
    }
    __syncthreads();
    if (tid < 256) {
        int nd = tid >> 3;
        int node2 = blockIdx.x * 32 + nd;
        if (node2 < n) {
            int cg = (tid & 7) * 5;
            float a5[5];
#pragma unroll
            for (int j = 0; j < 5; ++j) a5[j] = sY[nd * C + cg + j] + sb[cg + j];
            float m = a5[0];
#pragma unroll
            for (int j = 1; j < 5; ++j) m = fmaxf(m, a5[j]);
#pragma unroll
            for (int off = 1; off < 8; off <<= 1) m = fmaxf(m, __shfl_xor(m, off, 8));
            float ssum = 0.0f;
#pragma unroll
            for (int j = 0; j < 5; ++j) ssum += __expf(a5[j] - m);
#pragma unroll
            for (int off = 1; off < 8; off <<= 1) ssum += __shfl_xor(ssum, off, 8);
            float ls = logf(ssum) + m;
            float* o = out + (size_t)node2 * C + cg;
#pragma unroll
            for (int j = 0; j < 5; ++j) o[j] = a5[j] - ls;
        }
    }
}

extern "C" void kernel_launch(void* const* d_in, const int* in_sizes, int n_in,
                              void* d_out, int out_size, void* d_ws, size_t ws_size,
                              hipStream_t stream) {
    const float* x  = (const float*)d_in[0];
    const int*   ei = (const int*)d_in[1];   // [2, E] flat: row0 = src, row1 = dst
    const float* W  = (const float*)d_in[2]; // [D, C] row-major
    const float* b  = (const float*)d_in[3];
    float* out = (float*)d_out;

    const int N = in_sizes[0] / D;
    const int E = in_sizes[1] / 2;
    const int* src = ei;
    const int* dst = ei + E;

    // Workspace: dis[N] | cnt16[N*16] | rowptr[N+1] | bsum[512] | rank[E] | srcs[E]
    //            | ybuf0[N*C] | ybuf1[N*C]   (~52 MB)
    size_t npad = ((size_t)N + 256) & ~(size_t)255;
    size_t epad = ((size_t)E + 255) & ~(size_t)255;
    char* p = (char*)d_ws;
    float* dis    = (float*)p;  p += npad * 4;
    int*   cnt16  = (int*)p;    p += npad * CSTRIDE * 4;
    int*   rowptr = (int*)p;    p += npad * 4;
    int*   bsum   = (int*)p;    p += 512 * 4;
    int*   rank   = (int*)p;    p += epad * 4;
    int*   srcs   = (int*)p;    p += epad * 4;
    float* ybuf0  = (float*)p;  p += (size_t)N * C * 4;
    float* ybuf1  = (float*)p;

    const int TB = 256;
    int nb_n = (N + TB - 1) / TB;
    int nb_e = (E + TB - 1) / TB;
    int nb_scan = (N + SCAN_B - 1) / SCAN_B;  // 391 <= 512

    // ---- zero padded histogram ----
    int n4 = N * (CSTRIDE / 4);
    zero_kernel<<<(n4 + TB - 1) / TB, TB, 0, stream>>>((int4*)cnt16, n4);

    // ---- merged: count_rank || proj (independent; proj hides under atomics) ----
    int nb_p = (N + HN - 1) / HN;     // 3125
    count_proj_kernel<<<nb_e + nb_p, 256, 0, stream>>>(dst, cnt16, rank, E,
                                                       x, W, ybuf0, N, nb_p);

    // ---- scan (+dis) -> rowptr ----
    scan_block_kernel<<<nb_scan, SCAN_B, 0, stream>>>(cnt16, rowptr, bsum, dis, N);
    scan_bsum_kernel<<<1, 512, 0, stream>>>(bsum, nb_scan);
    add_off_kernel<<<nb_n, TB, 0, stream>>>(rowptr, bsum, N, E);
    fill_kernel<<<nb_e, TB, 0, stream>>>(src, dst, rowptr, rank, srcs, E);

    // ---- K=3 hops on Y; hop 3 fused with bias+log_softmax ----
    int nb_g = ((N * 10) + TB - 1) / TB;
    gather40_kernel<<<nb_g, TB, 0, stream>>>(ybuf0, ybuf1, rowptr, srcs, dis, N);
    gather40_kernel<<<nb_g, TB, 0, stream>>>(ybuf1, ybuf0, rowptr, srcs, dis, N);
    int nb_l = (N + 31) / 32;
    gather40_lsm_kernel<<<nb_l, 320, 0, stream>>>(ybuf0, b, out, rowptr, srcs, dis, N);
}

// Round 6
// 224.393 us; speedup vs baseline: 2.6034x; 1.2654x over previous
//
#include <hip/hip_runtime.h>

#define D 128
#define C 40
#define SCAN_B 256
#define HN 32

// bf16 <-> f32 (bf16 stored as raw ushort; f2bf = round-to-nearest-even)
__device__ __forceinline__ float bf2f(unsigned short u) {
    union { unsigned int i; float f; } v; v.i = ((unsigned int)u) << 16; return v.f;
}
__device__ __forceinline__ unsigned short f2bf(float f) {
    unsigned int x = __float_as_uint(f);
    unsigned int r = (x + 0x7FFFu + ((x >> 16) & 1u)) >> 16;
    return (unsigned short)r;
}

// ---- zero histogram ----
__global__ void zero_kernel(int4* __restrict__ cntv, int n4) {
    int i = blockIdx.x * blockDim.x + threadIdx.x;
    if (i < n4) cntv[i] = make_int4(0, 0, 0, 0);
}

// ---- merged: count+rank || projection Y = X W (bf16 out) ----
// proj: 32 nodes/block, x-tile (bf16) + W (f32) in LDS, 8 lanes x 5 cols per node.
__global__ void count_proj_kernel(const int* __restrict__ dst, int* __restrict__ cnt,
                                  int* __restrict__ rank, int E,
                                  const float* __restrict__ x, const float* __restrict__ W,
                                  unsigned short* __restrict__ y, int n, int nb_p) {
    __shared__ unsigned short sXbf[HN * 136];  // stride 136: 8B-aligned ushort4, conflict-free
    __shared__ float sW[D * C];
    int bid = blockIdx.x;
    int tid = threadIdx.x;
    int role, sub;  // role 0 = count, 1 = proj
    if (bid < 2 * nb_p) { role = bid & 1; sub = bid >> 1; }
    else { role = 0; sub = bid - nb_p; }

    if (role == 0) {
        int e = sub * 256 + tid;
        if (e < E) rank[e] = atomicAdd(&cnt[dst[e]], 1);
        return;
    }

    // ---- projection role ----
    int base = sub * HN;
    for (int i = tid; i < D * C; i += 256) sW[i] = W[i];
    {
        const float4* xi = (const float4*)(x + (size_t)base * D);
        for (int i = tid; i < HN * 32; i += 256) {
            int r = i >> 5, c4 = i & 31;
            float4 v = xi[i];
            ushort4 u;
            u.x = f2bf(v.x); u.y = f2bf(v.y); u.z = f2bf(v.z); u.w = f2bf(v.w);
            *((ushort4*)&sXbf[r * 136 + c4 * 4]) = u;
        }
    }
    __syncthreads();
    int nd = tid >> 3;
    int cg = (tid & 7) * 5;
    float acc[5];
#pragma unroll
    for (int j = 0; j < 5; ++j) acc[j] = 0.0f;
    const unsigned short* xr = &sXbf[nd * 136];
    for (int d = 0; d < D; ++d) {
        float xv = bf2f(xr[d]);
        const float* wr = &sW[d * C + cg];
#pragma unroll
        for (int j = 0; j < 5; ++j) acc[j] += xv * wr[j];
    }
    int node = base + nd;
    if (node < n) {
        unsigned short* o = y + (size_t)node * C + cg;
#pragma unroll
        for (int j = 0; j < 5; ++j) o[j] = f2bf(acc[j]);
    }
}

// ---- exclusive scan over cnt -> rowptr; also emits dis = rsqrt(1+cnt) ----
__global__ void scan_block_kernel(const int* __restrict__ cnt, int* __restrict__ rowptr,
                                  int* __restrict__ bsum, float* __restrict__ dis, int n) {
    __shared__ int s[SCAN_B];
    int i = blockIdx.x * SCAN_B + threadIdx.x;
    int v = (i < n) ? cnt[i] : 0;
    if (i < n) dis[i] = rsqrtf(1.0f + (float)v);
    s[threadIdx.x] = v;
    __syncthreads();
    for (int off = 1; off < SCAN_B; off <<= 1) {
        int t = (threadIdx.x >= off) ? s[threadIdx.x - off] : 0;
        __syncthreads();
        s[threadIdx.x] += t;
        __syncthreads();
    }
    if (i < n) rowptr[i] = s[threadIdx.x] - v;  // exclusive within block
    if (threadIdx.x == SCAN_B - 1) bsum[blockIdx.x] = s[SCAN_B - 1];
}

__global__ void scan_bsum_kernel(int* __restrict__ bsum, int nb) {
    __shared__ int s[512];
    int v = (threadIdx.x < nb) ? bsum[threadIdx.x] : 0;
    s[threadIdx.x] = v;
    __syncthreads();
    for (int off = 1; off < 512; off <<= 1) {
        int t = (threadIdx.x >= off) ? s[threadIdx.x - off] : 0;
        __syncthreads();
        s[threadIdx.x] += t;
        __syncthreads();
    }
    if (threadIdx.x < nb) bsum[threadIdx.x] = s[threadIdx.x] - v;  // exclusive
}

__global__ void add_off_kernel(int* __restrict__ rowptr, const int* __restrict__ bsum,
                               int n, int E) {
    int i = blockIdx.x * blockDim.x + threadIdx.x;
    if (i < n) rowptr[i] += bsum[i >> 8];
    if (i == 0) rowptr[n] = E;
}

// ---- fill CSR: one scattered 4B store per edge (rank precomputed) ----
__global__ void fill_kernel(const int* __restrict__ src, const int* __restrict__ dst,
                            const int* __restrict__ rowptr, const int* __restrict__ rank,
                            int* __restrict__ srcs, int E) {
    int e = blockIdx.x * blockDim.x + threadIdx.x;
    if (e >= E) return;
    srcs[rowptr[dst[e]] + rank[e]] = src[e];
}

// ---- one propagation hop on bf16 Y: 10 lanes per node, one ushort4 (4 cols) each ----
// fp32 accumulate, bf16 store.
__global__ void gather40_kernel(const unsigned short* __restrict__ yin,
                                unsigned short* __restrict__ yout,
                                const int* __restrict__ rowptr, const int* __restrict__ srcs,
                                const float* __restrict__ dis, int n) {
    int gtid = blockIdx.x * blockDim.x + threadIdx.x;
    int node = gtid / 10;
    int ch = gtid - node * 10;
    if (node >= n) return;
    const ushort4* yi = (const ushort4*)yin;
    float dd = dis[node];
    ushort4 sv = yi[(size_t)node * 10 + ch];
    float ax = dd * bf2f(sv.x), ay = dd * bf2f(sv.y);
    float az = dd * bf2f(sv.z), aw = dd * bf2f(sv.w);
    int beg = rowptr[node], end = rowptr[node + 1];
    int e = beg;
    for (; e + 4 <= end; e += 4) {
        int s0 = srcs[e + 0], s1 = srcs[e + 1], s2 = srcs[e + 2], s3 = srcs[e + 3];
        float w0 = dis[s0], w1 = dis[s1], w2 = dis[s2], w3 = dis[s3];
        ushort4 v0 = yi[(size_t)s0 * 10 + ch];
        ushort4 v1 = yi[(size_t)s1 * 10 + ch];
        ushort4 v2 = yi[(size_t)s2 * 10 + ch];
        ushort4 v3 = yi[(size_t)s3 * 10 + ch];
        ax += w0 * bf2f(v0.x); ay += w0 * bf2f(v0.y); az += w0 * bf2f(v0.z); aw += w0 * bf2f(v0.w);
        ax += w1 * bf2f(v1.x); ay += w1 * bf2f(v1.y); az += w1 * bf2f(v1.z); aw += w1 * bf2f(v1.w);
        ax += w2 * bf2f(v2.x); ay += w2 * bf2f(v2.y); az += w2 * bf2f(v2.z); aw += w2 * bf2f(v2.w);
        ax += w3 * bf2f(v3.x); ay += w3 * bf2f(v3.y); az += w3 * bf2f(v3.z); aw += w3 * bf2f(v3.w);
    }
    for (; e < end; ++e) {
        int sv2 = srcs[e];
        float w = dis[sv2];
        ushort4 v = yi[(size_t)sv2 * 10 + ch];
        ax += w * bf2f(v.x); ay += w * bf2f(v.y); az += w * bf2f(v.z); aw += w * bf2f(v.w);
    }
    ax *= dd; ay *= dd; az *= dd; aw *= dd;
    ushort4 o;
    o.x = f2bf(ax); o.y = f2bf(ay); o.z = f2bf(az); o.w = f2bf(aw);
    ((ushort4*)yout)[(size_t)node * 10 + ch] = o;
}

// ---- final hop fused with bias + log_softmax. Block = 320 = 32 nodes x 10 lanes. ----
__global__ void __launch_bounds__(320)
gather40_lsm_kernel(const unsigned short* __restrict__ yin, const float* __restrict__ b,
                    float* __restrict__ out, const int* __restrict__ rowptr,
                    const int* __restrict__ srcs, const float* __restrict__ dis, int n) {
    __shared__ float sY[32 * C];
    __shared__ float sb[C];
    int tid = threadIdx.x;
    if (tid < C) sb[tid] = b[tid];
    int ndb = tid / 10;
    int ch = tid - ndb * 10;
    int node = blockIdx.x * 32 + ndb;
    if (node < n) {
        const ushort4* yi = (const ushort4*)yin;
        float dd = dis[node];
        ushort4 sv = yi[(size_t)node * 10 + ch];
        float ax = dd * bf2f(sv.x), ay = dd * bf2f(sv.y);
        float az = dd * bf2f(sv.z), aw = dd * bf2f(sv.w);
        int beg = rowptr[node], end = rowptr[node + 1];
        int e = beg;
        for (; e + 4 <= end; e += 4) {
            int s0 = srcs[e + 0], s1 = srcs[e + 1], s2 = srcs[e + 2], s3 = srcs[e + 3];
            float w0 = dis[s0], w1 = dis[s1], w2 = dis[s2], w3 = dis[s3];
            ushort4 v0 = yi[(size_t)s0 * 10 + ch];
            ushort4 v1 = yi[(size_t)s1 * 10 + ch];
            ushort4 v2 = yi[(size_t)s2 * 10 + ch];
            ushort4 v3 = yi[(size_t)s3 * 10 + ch];
            ax += w0 * bf2f(v0.x); ay += w0 * bf2f(v0.y); az += w0 * bf2f(v0.z); aw += w0 * bf2f(v0.w);
            ax += w1 * bf2f(v1.x); ay += w1 * bf2f(v1.y); az += w1 * bf2f(v1.z); aw += w1 * bf2f(v1.w);
            ax += w2 * bf2f(v2.x); ay += w2 * bf2f(v2.y); az += w2 * bf2f(v2.z); aw += w2 * bf2f(v2.w);
            ax += w3 * bf2f(v3.x); ay += w3 * bf2f(v3.y); az += w3 * bf2f(v3.z); aw += w3 * bf2f(v3.w);
        }
        for (; e < end; ++e) {
            int sv2 = srcs[e];
            float w = dis[sv2];
            ushort4 v = yi[(size_t)sv2 * 10 + ch];
            ax += w * bf2f(v.x); ay += w * bf2f(v.y); az += w * bf2f(v.z); aw += w * bf2f(v.w);
        }
        ax *= dd; ay *= dd; az *= dd; aw *= dd;
        ((float4*)sY)[tid] = make_float4(ax, ay, az, aw);
    }
    __syncthreads();
    if (tid < 256) {
        int nd = tid >> 3;
        int node2 = blockIdx.x * 32 + nd;
        if (node2 < n) {
            int cg = (tid & 7) * 5;
            float a5[5];
#pragma unroll
            for (int j = 0; j < 5; ++j) a5[j] = sY[nd * C + cg + j] + sb[cg + j];
            float m = a5[0];
#pragma unroll
            for (int j = 1; j < 5; ++j) m = fmaxf(m, a5[j]);
#pragma unroll
            for (int off = 1; off < 8; off <<= 1) m = fmaxf(m, __shfl_xor(m, off, 8));
            float ssum = 0.0f;
#pragma unroll
            for (int j = 0; j < 5; ++j) ssum += __expf(a5[j] - m);
#pragma unroll
            for (int off = 1; off < 8; off <<= 1) ssum += __shfl_xor(ssum, off, 8);
            float ls = logf(ssum) + m;
            float* o = out + (size_t)node2 * C + cg;
#pragma unroll
            for (int j = 0; j < 5; ++j) o[j] = a5[j] - ls;
        }
    }
}

extern "C" void kernel_launch(void* const* d_in, const int* in_sizes, int n_in,
                              void* d_out, int out_size, void* d_ws, size_t ws_size,
                              hipStream_t stream) {
    const float* x  = (const float*)d_in[0];
    const int*   ei = (const int*)d_in[1];   // [2, E] flat: row0 = src, row1 = dst
    const float* W  = (const float*)d_in[2]; // [D, C] row-major
    const float* b  = (const float*)d_in[3];
    float* out = (float*)d_out;

    const int N = in_sizes[0] / D;
    const int E = in_sizes[1] / 2;
    const int* src = ei;
    const int* dst = ei + E;

    // Workspace: dis[N] | cnt[N] | rowptr[N+1] | bsum[512] | rank[E] | srcs[E]
    //            | ybuf0[N*C] bf16 | ybuf1[N*C] bf16    (~30 MB)
    size_t npad = ((size_t)N + 256) & ~(size_t)255;
    size_t epad = ((size_t)E + 255) & ~(size_t)255;
    char* p = (char*)d_ws;
    float* dis    = (float*)p;  p += npad * 4;
    int*   cnt    = (int*)p;    p += npad * 4;
    int*   rowptr = (int*)p;    p += npad * 4;
    int*   bsum   = (int*)p;    p += 512 * 4;
    int*   rank   = (int*)p;    p += epad * 4;
    int*   srcs   = (int*)p;    p += epad * 4;
    size_t ypad = (((size_t)N * C * 2) + 255) & ~(size_t)255;
    unsigned short* ybuf0 = (unsigned short*)p;  p += ypad;
    unsigned short* ybuf1 = (unsigned short*)p;

    const int TB = 256;
    int nb_n = (N + TB - 1) / TB;
    int nb_e = (E + TB - 1) / TB;
    int nb_scan = (N + SCAN_B - 1) / SCAN_B;  // 391 <= 512

    // ---- zero histogram (N ints) ----
    int n4 = (N + 3) / 4;
    zero_kernel<<<(n4 + TB - 1) / TB, TB, 0, stream>>>((int4*)cnt, n4);

    // ---- merged: count_rank || proj ----
    int nb_p = (N + HN - 1) / HN;     // 3125
    count_proj_kernel<<<nb_e + nb_p, 256, 0, stream>>>(dst, cnt, rank, E,
                                                       x, W, ybuf0, N, nb_p);

    // ---- scan (+dis) -> rowptr ----
    scan_block_kernel<<<nb_scan, SCAN_B, 0, stream>>>(cnt, rowptr, bsum, dis, N);
    scan_bsum_kernel<<<1, 512, 0, stream>>>(bsum, nb_scan);
    add_off_kernel<<<nb_n, TB, 0, stream>>>(rowptr, bsum, N, E);
    fill_kernel<<<nb_e, TB, 0, stream>>>(src, dst, rowptr, rank, srcs, E);

    // ---- K=3 hops on bf16 Y; hop 3 fused with bias+log_softmax ----
    int nb_g = ((N * 10) + TB - 1) / TB;
    gather40_kernel<<<nb_g, TB, 0, stream>>>(ybuf0, ybuf1, rowptr, srcs, dis, N);
    gather40_kernel<<<nb_g, TB, 0, stream>>>(ybuf1, ybuf0, rowptr, srcs, dis, N);
    int nb_l = (N + 31) / 32;
    gather40_lsm_kernel<<<nb_l, 320, 0, stream>>>(ybuf0, b, out, rowptr, srcs, dis, N);
}

// Round 7
// 191.971 us; speedup vs baseline: 3.0431x; 1.1689x over previous
//
#include <hip/hip_runtime.h>

#define D 128
#define C 40
#define HN 32
#define NBH 256        // blocks participating in hist/partition (also their thread count)
#define BSH 8          // bucket = dst >> 8  (256 nodes per bucket)
#define NBKT_MAX 512

// bf16 <-> f32 (raw ushort storage; f2bf = round-to-nearest-even)
__device__ __forceinline__ float bf2f(unsigned short u) {
    union { unsigned int i; float f; } v; v.i = ((unsigned int)u) << 16; return v.f;
}
__device__ __forceinline__ unsigned short f2bf(float f) {
    unsigned int x = __float_as_uint(f);
    unsigned int r = (x + 0x7FFFu + ((x >> 16) & 1u)) >> 16;
    return (unsigned short)r;
}

// ---- K1: merged LDS-histogram (256 blocks) || projection y0 = X W (bf16) ----
__global__ void hist_proj_kernel(const int* __restrict__ dst, int* __restrict__ M, int E,
                                 const float* __restrict__ x, const float* __restrict__ W,
                                 unsigned short* __restrict__ y, int n, int nbkt) {
    __shared__ float sW[D * C];          // 20 KB (proj role)
    __shared__ int shist[NBKT_MAX];      // 2 KB  (hist role)
    int bid = blockIdx.x, tid = threadIdx.x;
    int role, sub;  // role 1 = hist, 0 = proj
    if (bid < 2 * NBH) { role = bid & 1; sub = bid >> 1; }
    else { role = 0; sub = bid - NBH; }

    if (role == 1) {
        for (int t = tid; t < nbkt; t += 256) shist[t] = 0;
        __syncthreads();
        for (int e = sub * 256 + tid; e < E; e += NBH * 256)
            atomicAdd(&shist[dst[e] >> BSH], 1);
        __syncthreads();
        for (int t = tid; t < nbkt; t += 256) M[t * NBH + sub] = shist[t];
        return;
    }

    // ---- projection role: no x staging (L1 broadcast), W in LDS ----
    for (int i = tid; i < D * C; i += 256) sW[i] = W[i];
    __syncthreads();
    int nd = tid >> 3;
    int cg = (tid & 7) * 5;
    int node = sub * HN + nd;
    if (node >= n) return;
    float acc[5] = {0.f, 0.f, 0.f, 0.f, 0.f};
    const float4* xr = (const float4*)(x + (size_t)node * D);
    for (int d4 = 0; d4 < 32; ++d4) {
        float4 xv = xr[d4];
        int dbase = d4 * 4;
        const float* wr0 = &sW[(dbase + 0) * C + cg];
        const float* wr1 = &sW[(dbase + 1) * C + cg];
        const float* wr2 = &sW[(dbase + 2) * C + cg];
        const float* wr3 = &sW[(dbase + 3) * C + cg];
#pragma unroll
        for (int j = 0; j < 5; ++j)
            acc[j] += xv.x * wr0[j] + xv.y * wr1[j] + xv.z * wr2[j] + xv.w * wr3[j];
    }
    unsigned short* o = y + (size_t)node * C + cg;
#pragma unroll
    for (int j = 0; j < 5; ++j) o[j] = f2bf(acc[j]);
}

// ---- K2: exclusive-scan each bucket's row of M (per-block counts); emit totals ----
__global__ void scanM_kernel(int* __restrict__ M, int* __restrict__ btot, int nbkt) {
    __shared__ int s[NBH];
    int b = blockIdx.x, tid = threadIdx.x;
    int v = M[b * NBH + tid];
    s[tid] = v;
    __syncthreads();
    for (int off = 1; off < NBH; off <<= 1) {
        int t = (tid >= off) ? s[tid - off] : 0;
        __syncthreads();
        s[tid] += t;
        __syncthreads();
    }
    M[b * NBH + tid] = s[tid] - v;   // exclusive
    if (tid == NBH - 1) btot[b] = s[tid];
}

// ---- K3: exclusive-scan bucket totals -> bucketBase; seal rowptr[N] ----
__global__ void scanB_kernel(const int* __restrict__ btot, int* __restrict__ bbase,
                             int* __restrict__ rowptr, int nbkt, int n, int E) {
    __shared__ int s[512];
    int tid = threadIdx.x;
    int v = (tid < nbkt) ? btot[tid] : 0;
    s[tid] = v;
    __syncthreads();
    for (int off = 1; off < 512; off <<= 1) {
        int t = (tid >= off) ? s[tid - off] : 0;
        __syncthreads();
        s[tid] += t;
        __syncthreads();
    }
    if (tid < nbkt) bbase[tid] = s[tid] - v;
    if (tid == 0) { bbase[nbkt] = E; rowptr[n] = E; }
}

// ---- K4: partition edges into bucket-grouped ebuf via LDS cursors ----
__global__ void part_kernel(const int* __restrict__ src, const int* __restrict__ dst,
                            const int* __restrict__ M, const int* __restrict__ bbase,
                            int* __restrict__ ebuf, int E, int nbkt) {
    __shared__ int scur[NBKT_MAX];
    int blk = blockIdx.x, tid = threadIdx.x;
    for (int t = tid; t < nbkt; t += 256) scur[t] = bbase[t] + M[t * NBH + blk];
    __syncthreads();
    for (int e = blk * 256 + tid; e < E; e += NBH * 256) {
        int d = dst[e];
        int pos = atomicAdd(&scur[d >> BSH], 1);
        ebuf[pos] = src[e] | ((d & ((1 << BSH) - 1)) << 17);
    }
}

// ---- K5: per-bucket CSR build (hist, scan, rank all in LDS) + z0 = dis*y0 ----
__global__ void bucket_csr_kernel(const int* __restrict__ ebuf, const int* __restrict__ bbase,
                                  int* __restrict__ rowptr, float* __restrict__ dis,
                                  int* __restrict__ srcs, unsigned short* __restrict__ y, int n) {
    __shared__ int scnt[256];
    __shared__ int s[256];
    __shared__ int sptr[256];
    __shared__ float sdis[256];
    int b = blockIdx.x, tid = threadIdx.x;
    int lo = bbase[b], hi = bbase[b + 1];
    scnt[tid] = 0;
    __syncthreads();
    for (int i = lo + tid; i < hi; i += 256)
        atomicAdd(&scnt[(ebuf[i] >> 17) & 255], 1);
    __syncthreads();
    int v = scnt[tid];
    s[tid] = v;
    __syncthreads();
    for (int off = 1; off < 256; off <<= 1) {
        int t = (tid >= off) ? s[tid - off] : 0;
        __syncthreads();
        s[tid] += t;
        __syncthreads();
    }
    int excl = s[tid] - v;
    int node = b * 256 + tid;
    float dv = rsqrtf(1.0f + (float)v);
    if (node < n) { rowptr[node] = lo + excl; dis[node] = dv; }
    sdis[tid] = dv;
    sptr[tid] = lo + excl;
    __syncthreads();
    for (int i = lo + tid; i < hi; i += 256) {
        int ev = ebuf[i];
        int pos = atomicAdd(&sptr[(ev >> 17) & 255], 1);
        srcs[pos] = ev & 0x1FFFF;
    }
    // epilogue: z0 = dis * y0 for this bucket's nodes (in place)
    __syncthreads();
    ushort4* y4 = (ushort4*)y;
    size_t base4 = (size_t)b * 256 * 10;
    for (int idx = tid; idx < 256 * 10; idx += 256) {
        int node2 = b * 256 + idx / 10;
        if (node2 < n) {
            ushort4 u = y4[base4 + idx];
            float sc = sdis[idx / 10];
            u.x = f2bf(sc * bf2f(u.x)); u.y = f2bf(sc * bf2f(u.y));
            u.z = f2bf(sc * bf2f(u.z)); u.w = f2bf(sc * bf2f(u.w));
            y4[base4 + idx] = u;
        }
    }
}

// ---- hop on z (bf16): z' = dd^2 * (z_self + sum_s z_s). No per-edge weights! ----
__global__ void gatherZ_kernel(const unsigned short* __restrict__ zin,
                               unsigned short* __restrict__ zout,
                               const int* __restrict__ rowptr, const int* __restrict__ srcs,
                               const float* __restrict__ dis, int n) {
    int gtid = blockIdx.x * blockDim.x + threadIdx.x;
    int node = gtid / 10;
    int ch = gtid - node * 10;
    if (node >= n) return;
    const ushort4* zi = (const ushort4*)zin;
    ushort4 sv = zi[(size_t)node * 10 + ch];
    float ax = bf2f(sv.x), ay = bf2f(sv.y), az = bf2f(sv.z), aw = bf2f(sv.w);
    int beg = rowptr[node], end = rowptr[node + 1];
    int e = beg;
    for (; e + 4 <= end; e += 4) {
        int s0 = srcs[e + 0], s1 = srcs[e + 1], s2 = srcs[e + 2], s3 = srcs[e + 3];
        ushort4 v0 = zi[(size_t)s0 * 10 + ch];
        ushort4 v1 = zi[(size_t)s1 * 10 + ch];
        ushort4 v2 = zi[(size_t)s2 * 10 + ch];
        ushort4 v3 = zi[(size_t)s3 * 10 + ch];
        ax += bf2f(v0.x) + bf2f(v1.x) + bf2f(v2.x) + bf2f(v3.x);
        ay += bf2f(v0.y) + bf2f(v1.y) + bf2f(v2.y) + bf2f(v3.y);
        az += bf2f(v0.z) + bf2f(v1.z) + bf2f(v2.z) + bf2f(v3.z);
        aw += bf2f(v0.w) + bf2f(v1.w) + bf2f(v2.w) + bf2f(v3.w);
    }
    for (; e < end; ++e) {
        ushort4 vv = zi[(size_t)srcs[e] * 10 + ch];
        ax += bf2f(vv.x); ay += bf2f(vv.y); az += bf2f(vv.z); aw += bf2f(vv.w);
    }
    float dd = dis[node];
    float sc = dd * dd;
    ushort4 o;
    o.x = f2bf(ax * sc); o.y = f2bf(ay * sc); o.z = f2bf(az * sc); o.w = f2bf(aw * sc);
    ((ushort4*)zout)[(size_t)node * 10 + ch] = o;
}

// ---- final hop (scale dd) fused with bias + log_softmax. Block = 320. ----
__global__ void __launch_bounds__(320)
gatherZ_lsm_kernel(const unsigned short* __restrict__ zin, const float* __restrict__ b,
                   float* __restrict__ out, const int* __restrict__ rowptr,
                   const int* __restrict__ srcs, const float* __restrict__ dis, int n) {
    __shared__ float sY[32 * C];
    __shared__ float sb[C];
    int tid = threadIdx.x;
    if (tid < C) sb[tid] = b[tid];
    int ndb = tid / 10;
    int ch = tid - ndb * 10;
    int node = blockIdx.x * 32 + ndb;
    if (node < n) {
        const ushort4* zi = (const ushort4*)zin;
        ushort4 sv = zi[(size_t)node * 10 + ch];
        float ax = bf2f(sv.x), ay = bf2f(sv.y), az = bf2f(sv.z), aw = bf2f(sv.w);
        int beg = rowptr[node], end = rowptr[node + 1];
        int e = beg;
        for (; e + 4 <= end; e += 4) {
            int s0 = srcs[e + 0], s1 = srcs[e + 1], s2 = srcs[e + 2], s3 = srcs[e + 3];
            ushort4 v0 = zi[(size_t)s0 * 10 + ch];
            ushort4 v1 = zi[(size_t)s1 * 10 + ch];
            ushort4 v2 = zi[(size_t)s2 * 10 + ch];
            ushort4 v3 = zi[(size_t)s3 * 10 + ch];
            ax += bf2f(v0.x) + bf2f(v1.x) + bf2f(v2.x) + bf2f(v3.x);
            ay += bf2f(v0.y) + bf2f(v1.y) + bf2f(v2.y) + bf2f(v3.y);
            az += bf2f(v0.z) + bf2f(v1.z) + bf2f(v2.z) + bf2f(v3.z);
            aw += bf2f(v0.w) + bf2f(v1.w) + bf2f(v2.w) + bf2f(v3.w);
        }
        for (; e < end; ++e) {
            ushort4 vv = zi[(size_t)srcs[e] * 10 + ch];
            ax += bf2f(vv.x); ay += bf2f(vv.y); az += bf2f(vv.z); aw += bf2f(vv.w);
        }
        float dd = dis[node];
        ((float4*)sY)[tid] = make_float4(ax * dd, ay * dd, az * dd, aw * dd);
    }
    __syncthreads();
    if (tid < 256) {
        int nd = tid >> 3;
        int node2 = blockIdx.x * 32 + nd;
        if (node2 < n) {
            int cg = (tid & 7) * 5;
            float a5[5];
#pragma unroll
            for (int j = 0; j < 5; ++j) a5[j] = sY[nd * C + cg + j] + sb[cg + j];
            float m = a5[0];
#pragma unroll
            for (int j = 1; j < 5; ++j) m = fmaxf(m, a5[j]);
#pragma unroll
            for (int off = 1; off < 8; off <<= 1) m = fmaxf(m, __shfl_xor(m, off, 8));
            float ssum = 0.0f;
#pragma unroll
            for (int j = 0; j < 5; ++j) ssum += __expf(a5[j] - m);
#pragma unroll
            for (int off = 1; off < 8; off <<= 1) ssum += __shfl_xor(ssum, off, 8);
            float ls = logf(ssum) + m;
            float* o = out + (size_t)node2 * C + cg;
#pragma unroll
            for (int j = 0; j < 5; ++j) o[j] = a5[j] - ls;
        }
    }
}

extern "C" void kernel_launch(void* const* d_in, const int* in_sizes, int n_in,
                              void* d_out, int out_size, void* d_ws, size_t ws_size,
                              hipStream_t stream) {
    const float* x  = (const float*)d_in[0];
    const int*   ei = (const int*)d_in[1];   // [2, E] flat: row0 = src, row1 = dst
    const float* W  = (const float*)d_in[2]; // [D, C] row-major
    const float* b  = (const float*)d_in[3];
    float* out = (float*)d_out;

    const int N = in_sizes[0] / D;
    const int E = in_sizes[1] / 2;
    const int* src = ei;
    const int* dst = ei + E;
    const int nbkt = (N + 255) >> BSH;       // 391 for N=100000 (<= NBKT_MAX)

    // Workspace: dis[N] | rowptr[N+1] | btot[NBKT_MAX] | bbase[NBKT_MAX+1] |
    //            M[nbkt*NBH] | ebuf[E] | srcs[E] | ybuf0 | ybuf1 (bf16)  (~31 MB)
    size_t npad = ((size_t)N + 256) & ~(size_t)255;
    size_t epad = ((size_t)E + 255) & ~(size_t)255;
    char* p = (char*)d_ws;
    float* dis    = (float*)p;  p += npad * 4;
    int*   rowptr = (int*)p;    p += npad * 4;
    int*   btot   = (int*)p;    p += NBKT_MAX * 4;
    int*   bbase  = (int*)p;    p += (NBKT_MAX + 1) * 4;
    int*   M      = (int*)p;    p += (size_t)NBKT_MAX * NBH * 4;
    int*   ebuf   = (int*)p;    p += epad * 4;
    int*   srcs   = (int*)p;    p += epad * 4;
    size_t ypad = (((size_t)N * C * 2) + 255) & ~(size_t)255;
    unsigned short* ybuf0 = (unsigned short*)p;  p += ypad;
    unsigned short* ybuf1 = (unsigned short*)p;

    const int TB = 256;
    int nb_p = (N + HN - 1) / HN;     // 3125

    // ---- CSR build + projection ----
    hist_proj_kernel<<<NBH + nb_p, TB, 0, stream>>>(dst, M, E, x, W, ybuf0, N, nbkt);
    scanM_kernel<<<nbkt, NBH, 0, stream>>>(M, btot, nbkt);
    scanB_kernel<<<1, 512, 0, stream>>>(btot, bbase, rowptr, nbkt, N, E);
    part_kernel<<<NBH, TB, 0, stream>>>(src, dst, M, bbase, ebuf, E, nbkt);
    bucket_csr_kernel<<<nbkt, TB, 0, stream>>>(ebuf, bbase, rowptr, dis, srcs, ybuf0, N);

    // ---- K=3 hops on z (bf16); hop 3 fused with bias+log_softmax ----
    int nb_g = ((N * 10) + TB - 1) / TB;
    gatherZ_kernel<<<nb_g, TB, 0, stream>>>(ybuf0, ybuf1, rowptr, srcs, dis, N);
    gatherZ_kernel<<<nb_g, TB, 0, stream>>>(ybuf1, ybuf0, rowptr, srcs, dis, N);
    int nb_l = (N + 31) / 32;
    gatherZ_lsm_kernel<<<nb_l, 320, 0, stream>>>(ybuf0, b, out, rowptr, srcs, dis, N);
}

// Round 8
// 173.515 us; speedup vs baseline: 3.3668x; 1.1064x over previous
//
#include <hip/hip_runtime.h>

#define D 128
#define C 40
#define NBH 256        // blocks participating in hist/partition (also their thread count)
#define BSH 8          // bucket = dst >> 8  (256 nodes per bucket)
#define NBKT_MAX 512

typedef __attribute__((ext_vector_type(8))) short s8v;
typedef __attribute__((ext_vector_type(4))) float f4v;

// bf16 <-> f32 (raw ushort storage; f2bf = round-to-nearest-even)
__device__ __forceinline__ float bf2f(unsigned short u) {
    union { unsigned int i; float f; } v; v.i = ((unsigned int)u) << 16; return v.f;
}
__device__ __forceinline__ unsigned short f2bf(float f) {
    unsigned int x = __float_as_uint(f);
    unsigned int r = (x + 0x7FFFu + ((x >> 16) & 1u)) >> 16;
    return (unsigned short)r;
}

// ---- K1: merged LDS-histogram (256 blocks) || MFMA projection y0 = X W (bf16) ----
// proj: per wave one 16-row tile; W fragments register-resident (loop-invariant B).
__global__ void hist_proj_kernel(const int* __restrict__ dst, int* __restrict__ M, int E,
                                 const float* __restrict__ x, const float* __restrict__ W,
                                 unsigned short* __restrict__ y, int n, int nbkt) {
    __shared__ int shist[NBKT_MAX];      // 2 KB (hist role only)
    int bid = blockIdx.x, tid = threadIdx.x;
    int role, sub;  // role 1 = hist, 0 = proj
    if (bid < 2 * NBH) { role = bid & 1; sub = bid >> 1; }
    else { role = 0; sub = bid - NBH; }

    if (role == 1) {
        for (int t = tid; t < nbkt; t += 256) shist[t] = 0;
        __syncthreads();
        for (int e = sub * 256 + tid; e < E; e += NBH * 256)
            atomicAdd(&shist[dst[e] >> BSH], 1);
        __syncthreads();
        for (int t = tid; t < nbkt; t += 256) M[t * NBH + sub] = shist[t];
        return;
    }

    // ---- projection role: MFMA 16x16x32 bf16, 16 rows per wave ----
    int wid = tid >> 6;
    int lane = tid & 63;
    int tile = sub * 4 + wid;               // 16-row tile
    if (tile * 16 >= n) return;             // N multiple of 16 -> no row guard needed
    int r = lane & 15;
    int kg = lane >> 4;                     // 0..3

    // B fragments: bfrag[ct][ks], ct = col-tile (cols ct*16+r), ks = K-step of 32
    s8v bfrag[3][4];
#pragma unroll
    for (int ct = 0; ct < 3; ++ct) {
        int col = ct * 16 + r;
#pragma unroll
        for (int ks = 0; ks < 4; ++ks) {
            s8v f;
#pragma unroll
            for (int j = 0; j < 8; ++j) {
                int k = ks * 32 + kg * 8 + j;
                float wv = (col < C) ? W[k * C + col] : 0.0f;
                f[j] = (short)f2bf(wv);
            }
            bfrag[ct][ks] = f;
        }
    }

    f4v acc0 = {0.f, 0.f, 0.f, 0.f};
    f4v acc1 = {0.f, 0.f, 0.f, 0.f};
    f4v acc2 = {0.f, 0.f, 0.f, 0.f};
    int row = tile * 16 + r;
    const float4* xrow = (const float4*)(x + (size_t)row * D);
#pragma unroll
    for (int ks = 0; ks < 4; ++ks) {
        int kb = ks * 32 + kg * 8;          // multiple of 8
        float4 u0 = xrow[kb >> 2];
        float4 u1 = xrow[(kb >> 2) + 1];
        s8v af;
        af[0] = (short)f2bf(u0.x); af[1] = (short)f2bf(u0.y);
        af[2] = (short)f2bf(u0.z); af[3] = (short)f2bf(u0.w);
        af[4] = (short)f2bf(u1.x); af[5] = (short)f2bf(u1.y);
        af[6] = (short)f2bf(u1.z); af[7] = (short)f2bf(u1.w);
        acc0 = __builtin_amdgcn_mfma_f32_16x16x32_bf16(af, bfrag[0][ks], acc0, 0, 0, 0);
        acc1 = __builtin_amdgcn_mfma_f32_16x16x32_bf16(af, bfrag[1][ks], acc1, 0, 0, 0);
        acc2 = __builtin_amdgcn_mfma_f32_16x16x32_bf16(af, bfrag[2][ks], acc2, 0, 0, 0);
    }
    // D layout: col = lane&15, row_in_tile = kg*4 + reg
#pragma unroll
    for (int rg = 0; rg < 4; ++rg) {
        int orow = tile * 16 + kg * 4 + rg;
        unsigned short* yr = y + (size_t)orow * C;
        yr[r] = f2bf(acc0[rg]);
        yr[16 + r] = f2bf(acc1[rg]);
        if (r < 8) yr[32 + r] = f2bf(acc2[rg]);
    }
}

// ---- K2: exclusive-scan each bucket's row of M (per-block counts); emit totals ----
__global__ void scanM_kernel(int* __restrict__ M, int* __restrict__ btot, int nbkt) {
    __shared__ int s[NBH];
    int b = blockIdx.x, tid = threadIdx.x;
    int v = M[b * NBH + tid];
    s[tid] = v;
    __syncthreads();
    for (int off = 1; off < NBH; off <<= 1) {
        int t = (tid >= off) ? s[tid - off] : 0;
        __syncthreads();
        s[tid] += t;
        __syncthreads();
    }
    M[b * NBH + tid] = s[tid] - v;   // exclusive
    if (tid == NBH - 1) btot[b] = s[tid];
}

// ---- K3: exclusive-scan bucket totals -> bucketBase; seal rowptr[N] ----
__global__ void scanB_kernel(const int* __restrict__ btot, int* __restrict__ bbase,
                             int* __restrict__ rowptr, int nbkt, int n, int E) {
    __shared__ int s[512];
    int tid = threadIdx.x;
    int v = (tid < nbkt) ? btot[tid] : 0;
    s[tid] = v;
    __syncthreads();
    for (int off = 1; off < 512; off <<= 1) {
        int t = (tid >= off) ? s[tid - off] : 0;
        __syncthreads();
        s[tid] += t;
        __syncthreads();
    }
    if (tid < nbkt) bbase[tid] = s[tid] - v;
    if (tid == 0) { bbase[nbkt] = E; rowptr[n] = E; }
}

// ---- K4: partition edges into bucket-grouped ebuf via LDS cursors ----
__global__ void part_kernel(const int* __restrict__ src, const int* __restrict__ dst,
                            const int* __restrict__ M, const int* __restrict__ bbase,
                            int* __restrict__ ebuf, int E, int nbkt) {
    __shared__ int scur[NBKT_MAX];
    int blk = blockIdx.x, tid = threadIdx.x;
    for (int t = tid; t < nbkt; t += 256) scur[t] = bbase[t] + M[t * NBH + blk];
    __syncthreads();
    for (int e = blk * 256 + tid; e < E; e += NBH * 256) {
        int d = dst[e];
        int pos = atomicAdd(&scur[d >> BSH], 1);
        ebuf[pos] = src[e] | ((d & ((1 << BSH) - 1)) << 17);
    }
}

// ---- K5: per-bucket CSR build (hist, scan, rank all in LDS) + z0 = dis*y0 ----
__global__ void bucket_csr_kernel(const int* __restrict__ ebuf, const int* __restrict__ bbase,
                                  int* __restrict__ rowptr, float* __restrict__ dis,
                                  int* __restrict__ srcs, unsigned short* __restrict__ y, int n) {
    __shared__ int scnt[256];
    __shared__ int s[256];
    __shared__ int sptr[256];
    __shared__ float sdis[256];
    int b = blockIdx.x, tid = threadIdx.x;
    int lo = bbase[b], hi = bbase[b + 1];
    scnt[tid] = 0;
    __syncthreads();
    for (int i = lo + tid; i < hi; i += 256)
        atomicAdd(&scnt[(ebuf[i] >> 17) & 255], 1);
    __syncthreads();
    int v = scnt[tid];
    s[tid] = v;
    __syncthreads();
    for (int off = 1; off < 256; off <<= 1) {
        int t = (tid >= off) ? s[tid - off] : 0;
        __syncthreads();
        s[tid] += t;
        __syncthreads();
    }
    int excl = s[tid] - v;
    int node = b * 256 + tid;
    float dv = rsqrtf(1.0f + (float)v);
    if (node < n) { rowptr[node] = lo + excl; dis[node] = dv; }
    sdis[tid] = dv;
    sptr[tid] = lo + excl;
    __syncthreads();
    for (int i = lo + tid; i < hi; i += 256) {
        int ev = ebuf[i];
        int pos = atomicAdd(&sptr[(ev >> 17) & 255], 1);
        srcs[pos] = ev & 0x1FFFF;
    }
    // epilogue: z0 = dis * y0 for this bucket's nodes (in place)
    __syncthreads();
    ushort4* y4 = (ushort4*)y;
    size_t base4 = (size_t)b * 256 * 10;
    for (int idx = tid; idx < 256 * 10; idx += 256) {
        int node2 = b * 256 + idx / 10;
        if (node2 < n) {
            ushort4 u = y4[base4 + idx];
            float sc = sdis[idx / 10];
            u.x = f2bf(sc * bf2f(u.x)); u.y = f2bf(sc * bf2f(u.y));
            u.z = f2bf(sc * bf2f(u.z)); u.w = f2bf(sc * bf2f(u.w));
            y4[base4 + idx] = u;
        }
    }
}

// ---- hop on z (bf16): z' = dd^2 * (z_self + sum_s z_s). No per-edge weights! ----
__global__ void gatherZ_kernel(const unsigned short* __restrict__ zin,
                               unsigned short* __restrict__ zout,
                               const int* __restrict__ rowptr, const int* __restrict__ srcs,
                               const float* __restrict__ dis, int n) {
    int gtid = blockIdx.x * blockDim.x + threadIdx.x;
    int node = gtid / 10;
    int ch = gtid - node * 10;
    if (node >= n) return;
    const ushort4* zi = (const ushort4*)zin;
    ushort4 sv = zi[(size_t)node * 10 + ch];
    float ax = bf2f(sv.x), ay = bf2f(sv.y), az = bf2f(sv.z), aw = bf2f(sv.w);
    int beg = rowptr[node], end = rowptr[node + 1];
    int e = beg;
    for (; e + 4 <= end; e += 4) {
        int s0 = srcs[e + 0], s1 = srcs[e + 1], s2 = srcs[e + 2], s3 = srcs[e + 3];
        ushort4 v0 = zi[(size_t)s0 * 10 + ch];
        ushort4 v1 = zi[(size_t)s1 * 10 + ch];
        ushort4 v2 = zi[(size_t)s2 * 10 + ch];
        ushort4 v3 = zi[(size_t)s3 * 10 + ch];
        ax += bf2f(v0.x) + bf2f(v1.x) + bf2f(v2.x) + bf2f(v3.x);
        ay += bf2f(v0.y) + bf2f(v1.y) + bf2f(v2.y) + bf2f(v3.y);
        az += bf2f(v0.z) + bf2f(v1.z) + bf2f(v2.z) + bf2f(v3.z);
        aw += bf2f(v0.w) + bf2f(v1.w) + bf2f(v2.w) + bf2f(v3.w);
    }
    for (; e < end; ++e) {
        ushort4 vv = zi[(size_t)srcs[e] * 10 + ch];
        ax += bf2f(vv.x); ay += bf2f(vv.y); az += bf2f(vv.z); aw += bf2f(vv.w);
    }
    float dd = dis[node];
    float sc = dd * dd;
    ushort4 o;
    o.x = f2bf(ax * sc); o.y = f2bf(ay * sc); o.z = f2bf(az * sc); o.w = f2bf(aw * sc);
    ((ushort4*)zout)[(size_t)node * 10 + ch] = o;
}

// ---- final hop (scale dd) fused with bias + log_softmax. Block = 320. ----
__global__ void __launch_bounds__(320)
gatherZ_lsm_kernel(const unsigned short* __restrict__ zin, const float* __restrict__ b,
                   float* __restrict__ out, const int* __restrict__ rowptr,
                   const int* __restrict__ srcs, const float* __restrict__ dis, int n) {
    __shared__ float sY[32 * C];
    __shared__ float sb[C];
    int tid = threadIdx.x;
    if (tid < C) sb[tid] = b[tid];
    int ndb = tid / 10;
    int ch = tid - ndb * 10;
    int node = blockIdx.x * 32 + ndb;
    if (node < n) {
        const ushort4* zi = (const ushort4*)zin;
        ushort4 sv = zi[(size_t)node * 10 + ch];
        float ax = bf2f(sv.x), ay = bf2f(sv.y), az = bf2f(sv.z), aw = bf2f(sv.w);
        int beg = rowptr[node], end = rowptr[node + 1];
        int e = beg;
        for (; e + 4 <= end; e += 4) {
            int s0 = srcs[e + 0], s1 = srcs[e + 1], s2 = srcs[e + 2], s3 = srcs[e + 3];
            ushort4 v0 = zi[(size_t)s0 * 10 + ch];
            ushort4 v1 = zi[(size_t)s1 * 10 + ch];
            ushort4 v2 = zi[(size_t)s2 * 10 + ch];
            ushort4 v3 = zi[(size_t)s3 * 10 + ch];
            ax += bf2f(v0.x) + bf2f(v1.x) + bf2f(v2.x) + bf2f(v3.x);
            ay += bf2f(v0.y) + bf2f(v1.y) + bf2f(v2.y) + bf2f(v3.y);
            az += bf2f(v0.z) + bf2f(v1.z) + bf2f(v2.z) + bf2f(v3.z);
            aw += bf2f(v0.w) + bf2f(v1.w) + bf2f(v2.w) + bf2f(v3.w);
        }
        for (; e < end; ++e) {
            ushort4 vv = zi[(size_t)srcs[e] * 10 + ch];
            ax += bf2f(vv.x); ay += bf2f(vv.y); az += bf2f(vv.z); aw += bf2f(vv.w);
        }
        float dd = dis[node];
        ((float4*)sY)[tid] = make_float4(ax * dd, ay * dd, az * dd, aw * dd);
    }
    __syncthreads();
    if (tid < 256) {
        int nd = tid >> 3;
        int node2 = blockIdx.x * 32 + nd;
        if (node2 < n) {
            int cg = (tid & 7) * 5;
            float a5[5];
#pragma unroll
            for (int j = 0; j < 5; ++j) a5[j] = sY[nd * C + cg + j] + sb[cg + j];
            float m = a5[0];
#pragma unroll
            for (int j = 1; j < 5; ++j) m = fmaxf(m, a5[j]);
#pragma unroll
            for (int off = 1; off < 8; off <<= 1) m = fmaxf(m, __shfl_xor(m, off, 8));
            float ssum = 0.0f;
#pragma unroll
            for (int j = 0; j < 5; ++j) ssum += __expf(a5[j] - m);
#pragma unroll
            for (int off = 1; off < 8; off <<= 1) ssum += __shfl_xor(ssum, off, 8);
            float ls = logf(ssum) + m;
            float* o = out + (size_t)node2 * C + cg;
#pragma unroll
            for (int j = 0; j < 5; ++j) o[j] = a5[j] - ls;
        }
    }
}

extern "C" void kernel_launch(void* const* d_in, const int* in_sizes, int n_in,
                              void* d_out, int out_size, void* d_ws, size_t ws_size,
                              hipStream_t stream) {
    const float* x  = (const float*)d_in[0];
    const int*   ei = (const int*)d_in[1];   // [2, E] flat: row0 = src, row1 = dst
    const float* W  = (const float*)d_in[2]; // [D, C] row-major
    const float* b  = (const float*)d_in[3];
    float* out = (float*)d_out;

    const int N = in_sizes[0] / D;
    const int E = in_sizes[1] / 2;
    const int* src = ei;
    const int* dst = ei + E;
    const int nbkt = (N + 255) >> BSH;       // 391 for N=100000 (<= NBKT_MAX)

    // Workspace: dis[N] | rowptr[N+1] | btot | bbase | M[nbkt*NBH] | ebuf[E] |
    //            srcs[E] | ybuf0 | ybuf1 (bf16)    (~31 MB)
    size_t npad = ((size_t)N + 256) & ~(size_t)255;
    size_t epad = ((size_t)E + 255) & ~(size_t)255;
    char* p = (char*)d_ws;
    float* dis    = (float*)p;  p += npad * 4;
    int*   rowptr = (int*)p;    p += npad * 4;
    int*   btot   = (int*)p;    p += NBKT_MAX * 4;
    int*   bbase  = (int*)p;    p += (NBKT_MAX + 1) * 4;
    int*   M      = (int*)p;    p += (size_t)NBKT_MAX * NBH * 4;
    int*   ebuf   = (int*)p;    p += epad * 4;
    int*   srcs   = (int*)p;    p += epad * 4;
    size_t ypad = (((size_t)N * C * 2) + 255) & ~(size_t)255;
    unsigned short* ybuf0 = (unsigned short*)p;  p += ypad;
    unsigned short* ybuf1 = (unsigned short*)p;

    const int TB = 256;
    int ntile = (N + 15) / 16;               // 6250
    int nb_p = (ntile + 3) / 4;              // 1563 proj blocks (4 waves x 16 rows)

    // ---- CSR build + projection ----
    hist_proj_kernel<<<NBH + nb_p, TB, 0, stream>>>(dst, M, E, x, W, ybuf0, N, nbkt);
    scanM_kernel<<<nbkt, NBH, 0, stream>>>(M, btot, nbkt);
    scanB_kernel<<<1, 512, 0, stream>>>(btot, bbase, rowptr, nbkt, N, E);
    part_kernel<<<NBH, TB, 0, stream>>>(src, dst, M, bbase, ebuf, E, nbkt);
    bucket_csr_kernel<<<nbkt, TB, 0, stream>>>(ebuf, bbase, rowptr, dis, srcs, ybuf0, N);

    // ---- K=3 hops on z (bf16); hop 3 fused with bias+log_softmax ----
    int nb_g = ((N * 10) + TB - 1) / TB;
    gatherZ_kernel<<<nb_g, TB, 0, stream>>>(ybuf0, ybuf1, rowptr, srcs, dis, N);
    gatherZ_kernel<<<nb_g, TB, 0, stream>>>(ybuf1, ybuf0, rowptr, srcs, dis, N);
    int nb_l = (N + 31) / 32;
    gatherZ_lsm_kernel<<<nb_l, 320, 0, stream>>>(ybuf0, b, out, rowptr, srcs, dis, N);
}